// Round 20
// baseline (71.228 us; speedup 1.0000x reference)
//
#include <hip/hip_runtime.h>

typedef int   v8i    __attribute__((ext_vector_type(8)));
typedef float f32x16 __attribute__((ext_vector_type(16)));

#define NI 256
#define NT 256
#define NL 32
#define NE 128
#define HW 49
#define NEG_INF (-3.0e38f)
#define SCALE1 0x7F7F7F7F   // e8m0 = 127 -> x1.0, all blocks

// wsB layout (fp8 e4m3, MFMA 32x32x64 fragment-linear), validated R15-R19:
//  frag gw = t*2+ks, byte j of lane l = txt[t, l&31, e=ks*64+(l>>5)*32+j] (1MB)
// A is converted IN-WAVE in main (same k<->(lane,byte) map -> permutation
// cancels; no wsA, no A-prep, no A first-touch coldness).

__device__ __forceinline__ unsigned char f32_to_e4m3(float f)
{
    unsigned fb = __float_as_uint(f);
    unsigned s  = (fb >> 24) & 0x80;
    int      e  = (int)((fb >> 23) & 0xFF);
    unsigned m  = fb & 0x7FFFFF;
    int ne = e - 120;                    // e - 127 + 7
    if (ne <= 0)  return (unsigned char)s;          // flush tiny -> +-0
    if (ne > 15) { ne = 15; m = 0x600000; }         // huge -> max (won't occur)
    unsigned base = ((unsigned)ne << 3) | (m >> 20);
    unsigned rem  = m & 0xFFFFF;
    if (rem > 0x80000 || (rem == 0x80000 && (base & 1))) base++;   // RNE
    if (base > 0x7E) base = 0x7E;                   // saturate to 448
    return (unsigned char)(s | base);
}

// ---------- pre-kernel: B-only, one text per block, XCD-PINNED ----------
// Block bb (XCD bb%8) converts text t = (bb&7)*32 + (bb>>3), so chunk(t)=t>>5
// == bb%8 == the XCD of every main-kernel reader (main bid%8 == tb == t>>5).
// B lands in its consumers' home L2.
__global__ __launch_bounds__(256, 4)
void prep_kernel(const float* __restrict__ txt,
                 unsigned char* __restrict__ wsB)
{
    const int tid  = threadIdx.x;
    const int wave = tid >> 6, lane = tid & 63;
    const int ml   = lane & 31, h = lane >> 5;
    const int bb   = blockIdx.x;
    const int t    = (bb & 7) * 32 + (bb >> 3);
    const int ks   = wave >> 1;          // k-slice 0/1
    const int eh   = wave & 1;           // 16-byte e-half within 32B run
    const int gw   = t * 2 + ks;
    const int e0   = ks * 64 + h * 32 + eh * 16;
    const float* p = txt + ((size_t)t * NL + ml) * NE + e0;
    union { unsigned char b[16]; int4 v; } u;
    #pragma unroll
    for (int q = 0; q < 4; ++q) {
        float4 f = *(const float4*)(p + q * 4);
        u.b[q*4+0] = f32_to_e4m3(f.x); u.b[q*4+1] = f32_to_e4m3(f.y);
        u.b[q*4+2] = f32_to_e4m3(f.z); u.b[q*4+3] = f32_to_e4m3(f.w);
    }
    *(int4*)(wsB + (size_t)gw * 2048 + lane * 32 + eh * 16) = u.v;
}

// ---------- main kernel: in-wave A-cvt + MX-fp8 K=64 pipeline ----------
// Grid 512 = 64 ig x 8 tb (32-text chunks) = 2 blocks/CU, zero tail, ZERO
// barriers. Wave converts its own image's A-frags at start (~1.3us, once);
// per text: 4 global dwordx4 B + 4 mfma_scale + fmax tree + ds_write.
__global__ __launch_bounds__(256, 3)
void clip_match_kernel(const float* __restrict__ img,
                       const unsigned char* __restrict__ wsB,
                       const int* __restrict__ tlen,
                       const float* __restrict__ nlt,
                       float* __restrict__ out)
{
    const int tid  = threadIdx.x;
    const int wave = tid >> 6, lane = tid & 63;
    const int ml   = lane & 31, h = lane >> 5;
    const int tb   = blockIdx.x & 7;     // text chunk (32 texts); == XCD
    const int ig   = blockIdx.x >> 3;    // image group (4 images)
    const int im   = ig * 4 + wave;      // this wave's image

    // per-(text): 64 partial maxima (h*32+col); stride 68 breaks epi banks
    __shared__ __align__(16) float colmax[4][NL][68];   // ~34.8 KB

    // ---- A fragments: convert own image in-register (no wsA) ----
    // frag (mt,ks) byte j of lane: img[im, e=ks*64+h*32+j, hw=min(mt*32+ml,48)]
    v8i aA0, aA1, aB0, aB1;
    {
        const float* __restrict__ pi = img + (size_t)im * (NE * HW);
        const int m0 = ml;
        const int m1 = (32 + ml > HW - 1) ? HW - 1 : 32 + ml;
        union { unsigned char b[32]; v8i v; } ua;
        #pragma unroll
        for (int fi = 0; fi < 4; ++fi) {
            const int mt = fi >> 1, ks = fi & 1;
            const int m  = mt ? m1 : m0;
            const float* q = pi + (ks * 64 + h * 32) * HW + m;
            #pragma unroll
            for (int j = 0; j < 32; ++j) ua.b[j] = f32_to_e4m3(q[j * HW]);
            if      (fi == 0) aA0 = ua.v;
            else if (fi == 1) aA1 = ua.v;
            else if (fi == 2) aB0 = ua.v;
            else              aB1 = ua.v;
        }
    }

    const unsigned char* csrc = wsB + (size_t)tb * NL * 4096 + lane * 32;
#define BFR(t, k) (*(const v8i*)(csrc + (size_t)(t) * 4096 + (k) * 2048))

#define COMPUTE(bk0, bk1, t)                                                \
    {                                                                       \
        f32x16 acc0 = __builtin_amdgcn_mfma_scale_f32_32x32x64_f8f6f4(      \
            aA0, bk0, (f32x16)(0.f), 0, 0, 0, SCALE1, 0, SCALE1);           \
        acc0 = __builtin_amdgcn_mfma_scale_f32_32x32x64_f8f6f4(             \
            aA1, bk1, acc0, 0, 0, 0, SCALE1, 0, SCALE1);                    \
        f32x16 acc1 = __builtin_amdgcn_mfma_scale_f32_32x32x64_f8f6f4(      \
            aB0, bk0, (f32x16)(0.f), 0, 0, 0, SCALE1, 0, SCALE1);           \
        acc1 = __builtin_amdgcn_mfma_scale_f32_32x32x64_f8f6f4(             \
            aB1, bk1, acc1, 0, 0, 0, SCALE1, 0, SCALE1);                    \
        /* partial max over this h-half's rows; C/D (shape-determined):    \
           col=lane&31, row r2=(reg&3)+8*(reg>>2)+4*h; acc0: m=r2 (all     \
           16 valid); acc1: m=32+r2 -> regs 0..7, +reg8 (m=48) iff h==0 */ \
        float t0[8];                                                        \
        _Pragma("unroll")                                                   \
        for (int k = 0; k < 8; ++k) t0[k] = fmaxf(acc0[2*k], acc0[2*k+1]);  \
        float t1[4];                                                        \
        _Pragma("unroll")                                                   \
        for (int k = 0; k < 4; ++k) t1[k] = fmaxf(t0[2*k], t0[2*k+1]);      \
        float a0m = fmaxf(fmaxf(t1[0], t1[1]), fmaxf(t1[2], t1[3]));        \
        float u0[4];                                                        \
        _Pragma("unroll")                                                   \
        for (int k = 0; k < 4; ++k) u0[k] = fmaxf(acc1[2*k], acc1[2*k+1]);  \
        float a1m = fmaxf(fmaxf(u0[0], u0[1]), fmaxf(u0[2], u0[3]));        \
        float ex  = (h == 0) ? acc1[8] : NEG_INF;                           \
        colmax[wave][t][lane] = fmaxf(fmaxf(a0m, a1m), ex);                 \
    }

    v8i c0 = BFR(0, 0), c1 = BFR(0, 1);
    #pragma unroll 1
    for (int it = 0; it < 16; ++it) {
        const int t = 2 * it;
        v8i n0 = BFR(t + 1, 0), n1 = BFR(t + 1, 1);
        COMPUTE(c0, c1, t)
        if (it < 15) { c0 = BFR(t + 2, 0); c1 = BFR(t + 2, 1); }
        COMPUTE(n0, n1, t + 1)
    }
#undef COMPUTE
#undef BFR

    // ---- epilogue: merge h-halves, sum 32 cols, write both mirrors ----
    {
        const float scale = expf(nlt[0]);
        const int t = ml;                    // text within chunk
        const float* r0 = &colmax[wave][t][h * 16];        // h-part 0 slice
        const float* r1 = &colmax[wave][t][32 + h * 16];   // h-part 1 slice
        float4 a0 = *(const float4*)(r0 + 0);
        float4 a1 = *(const float4*)(r0 + 4);
        float4 a2 = *(const float4*)(r0 + 8);
        float4 a3 = *(const float4*)(r0 + 12);
        float4 c0 = *(const float4*)(r1 + 0);
        float4 c1 = *(const float4*)(r1 + 4);
        float4 c2 = *(const float4*)(r1 + 8);
        float4 c3 = *(const float4*)(r1 + 12);
        float s = (fmaxf(a0.x, c0.x) + fmaxf(a0.y, c0.y))
                + (fmaxf(a0.z, c0.z) + fmaxf(a0.w, c0.w))
                + (fmaxf(a1.x, c1.x) + fmaxf(a1.y, c1.y))
                + (fmaxf(a1.z, c1.z) + fmaxf(a1.w, c1.w))
                + (fmaxf(a2.x, c2.x) + fmaxf(a2.y, c2.y))
                + (fmaxf(a2.z, c2.z) + fmaxf(a2.w, c2.w))
                + (fmaxf(a3.x, c3.x) + fmaxf(a3.y, c3.y))
                + (fmaxf(a3.z, c3.z) + fmaxf(a3.w, c3.w));
        s += __shfl_xor(s, 32);              // other 16-col slice
        if (h == 0) {
            int tg = tb * NL + t;
            float v = s * scale / (float)tlen[tg];
            out[im * NT + tg] = v;              // logits_per_image[i,t]
            out[NI * NT + tg * NI + im] = v;    // logits_per_text[t,i]
        }
    }
}

extern "C" void kernel_launch(void* const* d_in, const int* in_sizes, int n_in,
                              void* d_out, int out_size, void* d_ws, size_t ws_size,
                              hipStream_t stream)
{
    const float* img  = (const float*)d_in[0];
    const float* txt  = (const float*)d_in[1];
    const int*   tlen = (const int*)d_in[2];
    const float* nlt  = (const float*)d_in[3];
    float* out = (float*)d_out;

    unsigned char* wsB = (unsigned char*)d_ws;           // 1 MB

    prep_kernel<<<dim3(256), dim3(256), 0, stream>>>(txt, wsB);
    clip_match_kernel<<<dim3(512), dim3(256), 0, stream>>>(img, wsB, tlen, nlt, out);
}